// Round 7
// baseline (46.389 us; speedup 1.0000x reference)
//
#include <hip/hip_runtime.h>

#define GB 64
#define GN 128
#define F_OBS 64
#define F_TOT 80

#define NPROBS GB            // 64 probs blocks (one per batch, blockIdx 0..63)
#define ASPLIT 8             // i-splits per batch for A blocks
#define NA (GB * ASPLIT)     // 512 A blocks
#define IPB (GN / ASPLIT)    // 16 i-rows per A block
#define IPG 4                // i-rows per thread group (4 groups of 128 thr)
#define NTHREADS 512
#define DPT 16               // circular distances per probs thread (64/4)

// ONE dispatch, no scratch, no atomics, no fences, no memset (R2/R5 lessons).
// Heterogeneous grid:
//  * blocks 0..63   : probs[b]. Exploits logit symmetry: enumerate each
//    unordered pair once via circular distance d in [1,64] (partner row
//    (j+d)&127); weight 2 for d<64, 1 for d=64 (those pairs appear twice).
//    Halves probs work; zero lane divergence; block-internal fixed-order
//    reduction only.
//  * blocks 64..575 : A tile. A[i][j] = (logit>0) | (i==j) -- no exp/log at
//    all. 4 rows/thread, k-outer acc[4] (R4/R6 lesson: tiny live state, no
//    remat), row base wave-uniform via readfirstlane (R3 lesson: provably
//    scalar s_load on the SALU pipe).
__global__ __launch_bounds__(NTHREADS) void glcn_all(
    const float* __restrict__ h, const float* __restrict__ w,
    float* __restrict__ Aout, float* __restrict__ probs) {
  const int tid = threadIdx.x;
  const int j = tid & (GN - 1);
  const int g = __builtin_amdgcn_readfirstlane(tid >> 7);  // 0..3, wave-uniform

  if (blockIdx.x >= NPROBS) {
    // ---------------- A block ----------------
    const int ab    = blockIdx.x - NPROBS;
    const int b     = ab >> 3;                          // / ASPLIT
    const int ibase = (ab & (ASPLIT - 1)) * IPB + g * IPG;
    const float* rowj = h + ((size_t)(b * GN + j)) * F_TOT;      // per-lane
    const float* rows = h + ((size_t)(b * GN + ibase)) * F_TOT;  // scalar

    float acc[IPG];
#pragma unroll
    for (int ii = 0; ii < IPG; ++ii) acc[ii] = 0.f;

#pragma unroll
    for (int kq = 0; kq < F_OBS / 4; ++kq) {
      const float4 hv = *reinterpret_cast<const float4*>(rowj + 4 * kq);
      const float4 wv = *reinterpret_cast<const float4*>(w + 4 * kq);
#pragma unroll
      for (int ii = 0; ii < IPG; ++ii) {
        const float* ri = rows + ii * F_TOT + 4 * kq;   // s_load_dwordx4
        acc[ii] = fmaf(wv.x, fabsf(hv.x - ri[0]), acc[ii]);
        acc[ii] = fmaf(wv.y, fabsf(hv.y - ri[1]), acc[ii]);
        acc[ii] = fmaf(wv.z, fabsf(hv.z - ri[2]), acc[ii]);
        acc[ii] = fmaf(wv.w, fabsf(hv.w - ri[3]), acc[ii]);
      }
    }

    float* Abase = Aout + (size_t)b * GN * GN;
#pragma unroll
    for (int ii = 0; ii < IPG; ++ii) {
      const int i = ibase + ii;
      const float Aval = ((acc[ii] > 0.f) | (i == j)) ? 1.f : 0.f;
      Abase[(size_t)i * GN + j] = Aval;                 // coalesced in j
    }
  } else {
    // ---------------- probs block ----------------
    const int b = blockIdx.x;
    const float* hB   = h + (size_t)b * GN * F_TOT;
    const float* rowj = hB + (size_t)j * F_TOT;         // per-lane

    // Element offsets of my 16 partner rows: d = g*16 + 1 + dd.
    int off[DPT];
#pragma unroll
    for (int dd = 0; dd < DPT; ++dd)
      off[dd] = ((j + g * DPT + 1 + dd) & (GN - 1)) * F_TOT;

    float acc[DPT];
#pragma unroll
    for (int dd = 0; dd < DPT; ++dd) acc[dd] = 0.f;

#pragma unroll 4
    for (int kq = 0; kq < F_OBS / 4; ++kq) {
      const float4 hv = *reinterpret_cast<const float4*>(rowj + 4 * kq);
      const float4 wv = *reinterpret_cast<const float4*>(w + 4 * kq);
#pragma unroll
      for (int dd = 0; dd < DPT; ++dd) {
        const float* r = hB + off[dd] + 4 * kq;         // per-lane gather
        acc[dd] = fmaf(wv.x, fabsf(hv.x - r[0]), acc[dd]);
        acc[dd] = fmaf(wv.y, fabsf(hv.y - r[1]), acc[dd]);
        acc[dd] = fmaf(wv.z, fabsf(hv.z - r[2]), acc[dd]);
        acc[dd] = fmaf(wv.w, fabsf(hv.w - r[3]), acc[dd]);
      }
    }

    // selected = A?y:(1-y) = sigmoid(|x|); weight 2 per unordered pair,
    // except d==64 pairs which our enumeration visits twice (weight 1).
    float lsum = 0.f;
#pragma unroll
    for (int dd = 0; dd < DPT; ++dd) {
      const int d = g * DPT + 1 + dd;
      const float sel = 1.f / (1.f + __expf(-fabsf(acc[dd])));
      const float lt  = __logf(sel + 1e-8f);
      lsum += (d == 64) ? lt : 2.f * lt;
    }

    // Deterministic: wave shfl tree, then thread 0 sums 8 wave partials
    // in fixed index order.
#pragma unroll
    for (int o = 32; o > 0; o >>= 1) lsum += __shfl_down(lsum, o, 64);
    __shared__ float red[NTHREADS / 64];
    const int lane = tid & 63;
    const int wid  = tid >> 6;
    if (lane == 0) red[wid] = lsum;
    __syncthreads();
    if (tid == 0) {
      float s = 0.f;
#pragma unroll
      for (int q = 0; q < NTHREADS / 64; ++q) s += red[q];
      probs[b] = s;
    }
  }
}

extern "C" void kernel_launch(void* const* d_in, const int* in_sizes, int n_in,
                              void* d_out, int out_size, void* d_ws, size_t ws_size,
                              hipStream_t stream) {
  const float* h = (const float*)d_in[0];   // [64,128,80] f32
  const float* w = (const float*)d_in[1];   // [64,1] f32
  float* Aout  = (float*)d_out;                       // [64,128,128]
  float* probs = Aout + (size_t)GB * GN * GN;         // [64]

  glcn_all<<<NPROBS + NA, NTHREADS, 0, stream>>>(h, w, Aout, probs);
}

// Round 8
// 16.000 us; speedup vs baseline: 2.8993x; 2.8993x over previous
//
#include <hip/hip_runtime.h>

#define GB 64
#define GN 128
#define F_OBS 64
#define F_TOT 80
#define ISPLIT 32
#define IPB (GN / ISPLIT)   // 4 i-rows per block

// R6's proven structure (best: 18.9us) with ONE structural change: ISPLIT
// 16->32 (2048 blocks x 2 waves = 4 waves/SIMD instead of 2) to hide the
// s_load/L2 latency in the MAC loop. part[] is stored TRANSPOSED
// (part[q*GB+b]) so the reduce kernel reads fully coalesced.
//
// Standing lessons: no cross-block ordering (R2: 7x), no atomics to probs
// (R5: cross-XCD atomic suspicion), partner rows on the scalar pipe only
// (R7: per-lane gathers = 8x HBM fetch), k-outer + small acc to avoid
// own-row remat (R4/R6).
__global__ __launch_bounds__(128) void glcn_main(
    const float* __restrict__ h, const float* __restrict__ w,
    float* __restrict__ Aout, float* __restrict__ part) {
  const int blk = blockIdx.x;
  const int b  = blk >> 5;                    // / ISPLIT
  const int q  = blk & (ISPLIT - 1);          // i-split index
  const int is = q * IPB;                     // block-uniform
  const int j  = threadIdx.x;                 // 0..127

  const float* rowj = h + ((size_t)(b * GN + j)) * F_TOT;    // per-lane
  const float* rows = h + ((size_t)(b * GN + is)) * F_TOT;   // uniform->s_load

  float acc[IPB];
#pragma unroll
  for (int ii = 0; ii < IPB; ++ii) acc[ii] = 0.f;

#pragma unroll 4
  for (int kq = 0; kq < F_OBS / 4; ++kq) {
    const float4 hv = *reinterpret_cast<const float4*>(rowj + 4 * kq);
    const float4 wv = *reinterpret_cast<const float4*>(w + 4 * kq);  // scalar
#pragma unroll
    for (int ii = 0; ii < IPB; ++ii) {
      const float* ri = rows + ii * F_TOT + 4 * kq;   // scalar dwordx4
      acc[ii] = fmaf(wv.x, fabsf(hv.x - ri[0]), acc[ii]);
      acc[ii] = fmaf(wv.y, fabsf(hv.y - ri[1]), acc[ii]);
      acc[ii] = fmaf(wv.z, fabsf(hv.z - ri[2]), acc[ii]);
      acc[ii] = fmaf(wv.w, fabsf(hv.w - ri[3]), acc[ii]);
    }
  }

  // Epilogue. sigmoid(x)>0.5 <=> x>0; selected = A?y:(1-y) = sigmoid(|x|).
  float logsum = 0.f;
  float* Abase = Aout + (size_t)b * GN * GN;
#pragma unroll
  for (int ii = 0; ii < IPB; ++ii) {
    const int i = is + ii;
    const float x = acc[ii];
    const float sel = 1.f / (1.f + __expf(-fabsf(x)));
    const float lt  = __logf(sel + 1e-8f);
    float Aval = (x > 0.f) ? 1.f : 0.f;
    if (i == j) Aval = 1.f;     // diagonal: forced 1, excluded from log-sum
    else        logsum += lt;
    Abase[(size_t)i * GN + j] = Aval;   // lanes = consecutive j: coalesced
  }

  // Deterministic intra-block reduction (fixed shuffle-tree order).
#pragma unroll
  for (int off = 32; off > 0; off >>= 1)
    logsum += __shfl_down(logsum, off, 64);
  __shared__ float red[2];
  const int lane = threadIdx.x & 63;
  const int wid  = threadIdx.x >> 6;
  if (lane == 0) red[wid] = logsum;
  __syncthreads();
  // Transposed layout: consecutive b in consecutive addresses per q-slice.
  if (threadIdx.x == 0) part[q * GB + b] = red[0] + red[1];
}

// probs[b] = sum of the 32 slice partials, fixed order; each of the 32 loads
// is fully coalesced across the 64 threads (part is [ISPLIT][GB]).
__global__ __launch_bounds__(64) void glcn_reduce(
    const float* __restrict__ part, float* __restrict__ probs) {
  const int b = threadIdx.x;
  float s = 0.f;
#pragma unroll
  for (int q = 0; q < ISPLIT; ++q) s += part[q * GB + b];
  probs[b] = s;
}

extern "C" void kernel_launch(void* const* d_in, const int* in_sizes, int n_in,
                              void* d_out, int out_size, void* d_ws, size_t ws_size,
                              hipStream_t stream) {
  const float* h = (const float*)d_in[0];   // [64,128,80] f32
  const float* w = (const float*)d_in[1];   // [64,1] f32
  float* Aout  = (float*)d_out;                       // [64,128,128]
  float* probs = Aout + (size_t)GB * GN * GN;         // [64]
  float* part  = (float*)d_ws;                        // ISPLIT*GB floats

  glcn_main<<<GB * ISPLIT, 128, 0, stream>>>(h, w, Aout, part);
  glcn_reduce<<<1, 64, 0, stream>>>(part, probs);
}